// Round 6
// baseline (821.935 us; speedup 1.0000x reference)
//
#include <hip/hip_runtime.h>
#include <stdint.h>

// Tree-RNN forward, split-bf16 MFMA, round 6.
//   h0 = relu(leaf[8192,4096] @ W_emb^T + b_emb)
//   13x: h = relu(h[m,1024] @ W_comb^T + b_comb)   (m: 4096..1)
//   out[2] = h_root @ W_proj^T + b_proj
// fp32 via 3-product split: AB ~= AhBh + AlBh + AhBl.
// Round-6 changes: (1) register-tiled GEMMs (embed 128x128 w/ 2x2 frags/wave,
// combine 64x128 w/ 1x2), BK=64, hi/lo co-packed 256B LDS rows with XOR-16B
// swizzle (2-way conflicts = free); (2) levels m<=1024 + proj fused into one
// persistent 64-block kernel with device-scope atomic grid barriers.

typedef float  f32x16 __attribute__((ext_vector_type(16)));
typedef short  s16x8  __attribute__((ext_vector_type(8)));
typedef unsigned short u16;

__device__ __forceinline__ u16 f2bf_rne(float f) {
    union { float f; uint32_t u; } v; v.f = f;
    return (u16)((v.u + 0x7FFFu + ((v.u >> 16) & 1u)) >> 16);
}
__device__ __forceinline__ float bf2f(u16 h) {
    union { uint32_t u; float f; } v; v.u = ((uint32_t)h) << 16;
    return v.f;
}
__device__ __forceinline__ void split2(float f, u16& h, u16& l) {
    union { float f; uint32_t u; } v; v.f = f;
    h = (u16)(v.u >> 16);                       // trunc hi
    union { uint32_t u; float f; } hf; hf.u = v.u & 0xFFFF0000u;
    l = f2bf_rne(f - hf.f);                     // RNE lo
}

// u16 index into a [rows][128] tile row: [hi 64 elems | lo 64 elems] = 256 B,
// XOR 16B-slot swizzle -> column reads alias only 2-way (rows r, r+8 mod 16).
__device__ __forceinline__ int swz(int row, int p, int e) {
    return (row * 128 + p * 64 + e) ^ ((row & 15) << 3);
}

// fp32 -> (hi, lo) bf16 planes (RNE lo), vectorized by 4
__global__ __launch_bounds__(256) void split_kernel(
    const float* __restrict__ x, u16* __restrict__ hi, u16* __restrict__ lo, int n4)
{
    int i = blockIdx.x * 256 + threadIdx.x;
    if (i >= n4) return;
    float4 v = ((const float4*)x)[i];
    ushort4 h, l;
    split2(v.x, h.x, l.x);
    split2(v.y, h.y, l.y);
    split2(v.z, h.z, l.z);
    split2(v.w, h.w, l.w);
    ((ushort4*)hi)[i] = h;
    ((ushort4*)lo)[i] = l;
}

// ---------------- embedding GEMM: 128x128 tile, fp32 A split inline ----------
// grid (8192/128, 512/128) = (64,4) = 256 blocks. 4 waves 2x2, wave 64x64
// (2x2 frags of 32x32). BK=64 (4 k-slices of 16).
__global__ __launch_bounds__(256, 1) void gemm_emb(
    const float* __restrict__ Af,                                   // [8192][4096]
    const u16* __restrict__ Bhi_g, const u16* __restrict__ Blo_g,   // [512][4096]
    const float* __restrict__ bias,
    u16* __restrict__ Chi, u16* __restrict__ Clo)                   // [8192][512]
{
    constexpr int K = 4096, N = 512;
    __shared__ u16 Asw[128 * 128];   // 32 KB
    __shared__ u16 Bsw[128 * 128];   // 32 KB

    const int tid = threadIdx.x, wid = tid >> 6, lane = tid & 63;
    const int mb = blockIdx.x * 128, nb = blockIdx.y * 128;
    const int wm = (wid >> 1) * 64, wn = (wid & 1) * 64;
    const int sr = tid >> 1;             // staging row 0..127 (A and B)
    const int se = (tid & 1) * 32;       // k-elem base 0/32

    const float* pA  = Af    + (long)(mb + sr) * K + se;
    const u16*   pBh = Bhi_g + (long)(nb + sr) * K + se;
    const u16*   pBl = Blo_g + (long)(nb + sr) * K + se;

    f32x16 accA[2][2] = {};
    f32x16 accB[2][2] = {};
    float4 ra[8];
    s16x8  rbh[4], rbl[4];

    auto fetch = [&](int k0) {
#pragma unroll
        for (int i = 0; i < 8; ++i) ra[i] = *(const float4*)(pA + k0 + 4 * i);
#pragma unroll
        for (int i = 0; i < 4; ++i) {
            rbh[i] = *(const s16x8*)(pBh + k0 + 8 * i);
            rbl[i] = *(const s16x8*)(pBl + k0 + 8 * i);
        }
    };
    auto stage = [&]() {
#pragma unroll
        for (int q = 0; q < 4; ++q) {
            s16x8 hh, ll;
#pragma unroll
            for (int j = 0; j < 8; ++j) {
                float f = (j < 4) ? (&ra[2 * q].x)[j] : (&ra[2 * q + 1].x)[j - 4];
                u16 h, l; split2(f, h, l);
                hh[j] = (short)h; ll[j] = (short)l;
            }
            *(s16x8*)&Asw[swz(sr, 0, se + 8 * q)] = hh;
            *(s16x8*)&Asw[swz(sr, 1, se + 8 * q)] = ll;
            *(s16x8*)&Bsw[swz(sr, 0, se + 8 * q)] = rbh[q];
            *(s16x8*)&Bsw[swz(sr, 1, se + 8 * q)] = rbl[q];
        }
    };

    fetch(0);
    const int fr = lane & 31, ko = lane >> 5;
    for (int k0 = 0; k0 < K; k0 += 64) {
        stage();
        __syncthreads();
        if (k0 + 64 < K) fetch(k0 + 64);
#pragma unroll
        for (int s = 0; s < 4; ++s) {
            const int e = s * 16 + ko * 8;
            s16x8 ah[2], al[2], bh[2], bl[2];
#pragma unroll
            for (int i = 0; i < 2; ++i) {
                ah[i] = *(const s16x8*)&Asw[swz(wm + 32 * i + fr, 0, e)];
                al[i] = *(const s16x8*)&Asw[swz(wm + 32 * i + fr, 1, e)];
                bh[i] = *(const s16x8*)&Bsw[swz(wn + 32 * i + fr, 0, e)];
                bl[i] = *(const s16x8*)&Bsw[swz(wn + 32 * i + fr, 1, e)];
            }
#pragma unroll
            for (int i = 0; i < 2; ++i)
#pragma unroll
                for (int j = 0; j < 2; ++j) {
                    accA[i][j] = __builtin_amdgcn_mfma_f32_32x32x16_bf16(ah[i], bh[j], accA[i][j], 0, 0, 0);
                    accA[i][j] = __builtin_amdgcn_mfma_f32_32x32x16_bf16(al[i], bh[j], accA[i][j], 0, 0, 0);
                    accB[i][j] = __builtin_amdgcn_mfma_f32_32x32x16_bf16(ah[i], bl[j], accB[i][j], 0, 0, 0);
                }
        }
        __syncthreads();
    }

    const int fc = lane & 31;
#pragma unroll
    for (int i = 0; i < 2; ++i)
#pragma unroll
        for (int j = 0; j < 2; ++j) {
            const int col = nb + wn + 32 * j + fc;
            const float bv = bias[col];
#pragma unroll
            for (int reg = 0; reg < 16; ++reg) {
                const int row = mb + wm + 32 * i + (reg & 3) + 8 * (reg >> 2) + 4 * (lane >> 5);
                float v = fmaxf(accA[i][j][reg] + accB[i][j][reg] + bv, 0.f);
                u16 h = f2bf_rne(v);
                const long idx = (long)row * N + col;
                Chi[idx] = h;
                Clo[idx] = f2bf_rne(v - bf2f(h));
            }
        }
}

// ---------------- combine tile: 64x128, K=1024, bf16 hi/lo A ----------------
__device__ __forceinline__ void cmb_tile(
    u16* __restrict__ Asw, u16* __restrict__ Bsw,     // [64*128], [128*128]
    const u16* __restrict__ Ahi, const u16* __restrict__ Alo,  // [m][1024] view
    const u16* __restrict__ Whi, const u16* __restrict__ Wlo,  // [512][1024]
    const float* __restrict__ bias,
    u16* __restrict__ Ohi, u16* __restrict__ Olo,              // [m][512]
    int m, int mb, int nb)
{
    constexpr int K = 1024, N = 512;
    const int tid = threadIdx.x, wid = tid >> 6, lane = tid & 63;
    const int wm = (wid >> 1) * 32, wn = (wid & 1) * 64;
    const int ar = tid >> 2, ae = (tid & 3) * 16;    // A: 4 thr/row
    const int br = tid >> 1, be = (tid & 1) * 32;    // B: 2 thr/row
    const bool aval = (mb + ar) < m;
    const long aoff = (long)(mb + ar) * K + ae;
    const long boff = (long)(nb + br) * K + be;

    f32x16 accA[2] = {};
    f32x16 accB[2] = {};
    const s16x8 zz = {0, 0, 0, 0, 0, 0, 0, 0};
    s16x8 rah[2], ral[2], rbh[4], rbl[4];

    auto fetch = [&](int k0) {
        if (aval) {
            rah[0] = *(const s16x8*)(Ahi + aoff + k0);
            rah[1] = *(const s16x8*)(Ahi + aoff + k0 + 8);
            ral[0] = *(const s16x8*)(Alo + aoff + k0);
            ral[1] = *(const s16x8*)(Alo + aoff + k0 + 8);
        } else {
            rah[0] = zz; rah[1] = zz; ral[0] = zz; ral[1] = zz;
        }
#pragma unroll
        for (int i = 0; i < 4; ++i) {
            rbh[i] = *(const s16x8*)(Whi + boff + k0 + 8 * i);
            rbl[i] = *(const s16x8*)(Wlo + boff + k0 + 8 * i);
        }
    };
    auto stage = [&]() {
#pragma unroll
        for (int q = 0; q < 2; ++q) {
            *(s16x8*)&Asw[swz(ar, 0, ae + 8 * q)] = rah[q];
            *(s16x8*)&Asw[swz(ar, 1, ae + 8 * q)] = ral[q];
        }
#pragma unroll
        for (int q = 0; q < 4; ++q) {
            *(s16x8*)&Bsw[swz(br, 0, be + 8 * q)] = rbh[q];
            *(s16x8*)&Bsw[swz(br, 1, be + 8 * q)] = rbl[q];
        }
    };

    fetch(0);
    const int fr = lane & 31, ko = lane >> 5;
    for (int k0 = 0; k0 < K; k0 += 64) {
        stage();
        __syncthreads();
        if (k0 + 64 < K) fetch(k0 + 64);
#pragma unroll
        for (int s = 0; s < 4; ++s) {
            const int e = s * 16 + ko * 8;
            s16x8 ah = *(const s16x8*)&Asw[swz(wm + fr, 0, e)];
            s16x8 al = *(const s16x8*)&Asw[swz(wm + fr, 1, e)];
#pragma unroll
            for (int j = 0; j < 2; ++j) {
                s16x8 bh = *(const s16x8*)&Bsw[swz(wn + 32 * j + fr, 0, e)];
                s16x8 bl = *(const s16x8*)&Bsw[swz(wn + 32 * j + fr, 1, e)];
                accA[j] = __builtin_amdgcn_mfma_f32_32x32x16_bf16(ah, bh, accA[j], 0, 0, 0);
                accA[j] = __builtin_amdgcn_mfma_f32_32x32x16_bf16(al, bh, accA[j], 0, 0, 0);
                accB[j] = __builtin_amdgcn_mfma_f32_32x32x16_bf16(ah, bl, accB[j], 0, 0, 0);
            }
        }
        __syncthreads();
    }

    const int fc = lane & 31;
#pragma unroll
    for (int j = 0; j < 2; ++j) {
        const int col = nb + wn + 32 * j + fc;
        const float bv = bias[col];
#pragma unroll
        for (int reg = 0; reg < 16; ++reg) {
            const int row = mb + wm + (reg & 3) + 8 * (reg >> 2) + 4 * (lane >> 5);
            if (row < m) {
                float v = fmaxf(accA[j][reg] + accB[j][reg] + bv, 0.f);
                u16 h = f2bf_rne(v);
                const long idx = (long)row * N + col;
                Ohi[idx] = h;
                Olo[idx] = f2bf_rne(v - bf2f(h));
            }
        }
    }
}

// standalone combine kernel for big levels (m = 4096, 2048). grid (m/64, 4)
__global__ __launch_bounds__(256, 2) void gemm_cmb(
    const u16* __restrict__ Ahi, const u16* __restrict__ Alo,
    const u16* __restrict__ Whi, const u16* __restrict__ Wlo,
    const float* __restrict__ bias,
    u16* __restrict__ Ohi, u16* __restrict__ Olo, int m)
{
    __shared__ u16 Asw[64 * 128];    // 16 KB
    __shared__ u16 Bsw[128 * 128];   // 32 KB
    cmb_tile(Asw, Bsw, Ahi, Alo, Whi, Wlo, bias, Ohi, Olo,
             m, blockIdx.x * 64, blockIdx.y * 128);
}

// device-scope grid barrier (monotonic counter; bar memset to 0 per launch)
__device__ __forceinline__ void gridbar(unsigned int* bar, unsigned int tgt) {
    __threadfence();
    __syncthreads();
    if (threadIdx.x == 0) {
        __hip_atomic_fetch_add(bar, 1u, __ATOMIC_ACQ_REL, __HIP_MEMORY_SCOPE_AGENT);
        while (__hip_atomic_load(bar, __ATOMIC_ACQUIRE, __HIP_MEMORY_SCOPE_AGENT) < tgt)
            __builtin_amdgcn_s_sleep(8);
    }
    __syncthreads();
    __threadfence();
}

// fused small levels: m = 1024 .. 1 (11 levels) + root projection.
// 64 blocks = (mt 0..15) x (nt 0..3); all co-resident on 256 CUs.
__global__ __launch_bounds__(256) void fused_small(
    const u16* __restrict__ Whi, const u16* __restrict__ Wlo,
    const float* __restrict__ bias,
    u16* __restrict__ h0h, u16* __restrict__ h0l,   // in: [2048][512] (c2048 out)
    u16* __restrict__ h1h, u16* __restrict__ h1l,
    const float* __restrict__ Wp, const float* __restrict__ bp,
    float* __restrict__ outp,
    unsigned int* __restrict__ bar)
{
    __shared__ u16 Asw[64 * 128];
    __shared__ u16 Bsw[128 * 128];
    const int mt = blockIdx.x >> 2, nt = blockIdx.x & 3;
    u16 *ih = h0h, *il = h0l, *oh = h1h, *ol = h1l;
    unsigned int tgt = 0;

    for (int m = 1024; m >= 1; m >>= 1) {
        const int mtiles = (m + 63) >> 6;
        if (mt < mtiles)
            cmb_tile(Asw, Bsw, ih, il, Whi, Wlo, bias, oh, ol, m, mt * 64, nt * 128);
        tgt += 64;
        gridbar(bar, tgt);
        u16* t;
        t = ih; ih = oh; oh = t;
        t = il; il = ol; ol = t;
    }

    // root projection: out[c] = dot(h_root, W_proj[c]) + b[c]
    if (blockIdx.x == 0 && threadIdx.x < 128) {
        const int c = threadIdx.x >> 6, ln = threadIdx.x & 63;
        float s = 0.f;
#pragma unroll
        for (int j = 0; j < 8; ++j) {
            const int idx = ln + 64 * j;
            s = fmaf(bf2f(ih[idx]) + bf2f(il[idx]), Wp[c * 512 + idx], s);
        }
#pragma unroll
        for (int off = 32; off > 0; off >>= 1) s += __shfl_down(s, off);
        if (ln == 0) outp[c] = s + bp[c];
    }
}

extern "C" void kernel_launch(void* const* d_in, const int* in_sizes, int n_in,
                              void* d_out, int out_size, void* d_ws, size_t ws_size,
                              hipStream_t stream)
{
    const float* leaf   = (const float*)d_in[0];  // [8192,4096]
    const float* W_emb  = (const float*)d_in[1];  // [512,4096]
    const float* b_emb  = (const float*)d_in[2];  // [512]
    const float* W_comb = (const float*)d_in[3];  // [512,1024]
    const float* b_comb = (const float*)d_in[4];  // [512]
    const float* W_proj = (const float*)d_in[5];  // [2,512]
    const float* b_proj = (const float*)d_in[6];  // [2]
    float* out = (float*)d_out;

    u16* p = (u16*)d_ws;                       // ~35.7 MB total
    u16* WembHi  = p; p += (size_t)512 * 4096;
    u16* WembLo  = p; p += (size_t)512 * 4096;
    u16* WcombHi = p; p += (size_t)512 * 1024;
    u16* WcombLo = p; p += (size_t)512 * 1024;
    u16* h0h = p; p += (size_t)8192 * 512;
    u16* h0l = p; p += (size_t)8192 * 512;
    u16* h1h = p; p += (size_t)4096 * 512;
    u16* h1l = p; p += (size_t)4096 * 512;
    unsigned int* bar = (unsigned int*)p;

    hipMemsetAsync((void*)bar, 0, 64, stream);

    {   // weight splits (recomputed every call; ws is re-poisoned)
        int n4 = 512 * 4096 / 4;
        split_kernel<<<(n4 + 255) / 256, 256, 0, stream>>>(W_emb, WembHi, WembLo, n4);
        n4 = 512 * 1024 / 4;
        split_kernel<<<(n4 + 255) / 256, 256, 0, stream>>>(W_comb, WcombHi, WcombLo, n4);
    }

    // embedding: [8192,4096] -> [8192,512]
    gemm_emb<<<dim3(64, 4), 256, 0, stream>>>(
        leaf, WembHi, WembLo, b_emb, h0h, h0l);

    // big combine levels
    gemm_cmb<<<dim3(64, 4), 256, 0, stream>>>(   // m=4096: h0[8192x512] -> h1
        h0h, h0l, WcombHi, WcombLo, b_comb, h1h, h1l, 4096);
    gemm_cmb<<<dim3(32, 4), 256, 0, stream>>>(   // m=2048: h1[4096x512] -> h0
        h1h, h1l, WcombHi, WcombLo, b_comb, h0h, h0l, 2048);

    // fused m=1024..1 + projection
    fused_small<<<64, 256, 0, stream>>>(
        WcombHi, WcombLo, b_comb, h0h, h0l, h1h, h1l, W_proj, b_proj, out, bar);
}

// Round 7
// 727.408 us; speedup vs baseline: 1.1300x; 1.1300x over previous
//
#include <hip/hip_runtime.h>
#include <stdint.h>

// Tree-RNN forward, split-bf16 MFMA, round 7.
//   h0 = relu(leaf[8192,4096] @ W_emb^T + b_emb)
//   13x: h = relu(h[m,1024] @ W_comb^T + b_comb)   (m: 4096..1)
//   out[2] = h_root @ W_proj^T + b_proj
// fp32 via 3-product split: AB ~= AhBh + AlBh + AhBl.
// Round 7: per-level launches (round-6 grid-barrier fusion removed: device-scope
// fences invalidate L2 every level -> 37us/level, measured). Keeps round-6
// register-tiled GEMMs + XOR-swizzled LDS (bank conflicts measured 0).

typedef float  f32x16 __attribute__((ext_vector_type(16)));
typedef short  s16x8  __attribute__((ext_vector_type(8)));
typedef unsigned short u16;

__device__ __forceinline__ u16 f2bf_rne(float f) {
    union { float f; uint32_t u; } v; v.f = f;
    return (u16)((v.u + 0x7FFFu + ((v.u >> 16) & 1u)) >> 16);
}
__device__ __forceinline__ float bf2f(u16 h) {
    union { uint32_t u; float f; } v; v.u = ((uint32_t)h) << 16;
    return v.f;
}
__device__ __forceinline__ void split2(float f, u16& h, u16& l) {
    union { float f; uint32_t u; } v; v.f = f;
    h = (u16)(v.u >> 16);                       // trunc hi
    union { uint32_t u; float f; } hf; hf.u = v.u & 0xFFFF0000u;
    l = f2bf_rne(f - hf.f);                     // RNE lo
}

// u16 index into a [rows][128] tile row: [hi 64 | lo 64] = 256 B, XOR swizzle.
// Column reads alias only 2-way (free). Verified: SQ_LDS_BANK_CONFLICT = 0.
__device__ __forceinline__ int swz(int row, int p, int e) {
    return (row * 128 + p * 64 + e) ^ ((row & 15) << 3);
}

// fp32 -> (hi, lo) bf16 planes
__global__ __launch_bounds__(256) void split_kernel(
    const float* __restrict__ x, u16* __restrict__ hi, u16* __restrict__ lo, int n4)
{
    int i = blockIdx.x * 256 + threadIdx.x;
    if (i >= n4) return;
    float4 v = ((const float4*)x)[i];
    ushort4 h, l;
    split2(v.x, h.x, l.x);
    split2(v.y, h.y, l.y);
    split2(v.z, h.z, l.z);
    split2(v.w, h.w, l.w);
    ((ushort4*)hi)[i] = h;
    ((ushort4*)lo)[i] = l;
}

// ---------------- embedding GEMM: 128x128 tile, fp32 A split inline ----------
// grid (64, 4). 4 waves 2x2, wave 64x64 (2x2 frags of 32x32). BK=64.
__global__ __launch_bounds__(256, 1) void gemm_emb(
    const float* __restrict__ Af,                                   // [8192][4096]
    const u16* __restrict__ Bhi_g, const u16* __restrict__ Blo_g,   // [512][4096]
    const float* __restrict__ bias,
    u16* __restrict__ Chi, u16* __restrict__ Clo)                   // [8192][512]
{
    constexpr int K = 4096, N = 512;
    __shared__ u16 Asw[128 * 128];   // 32 KB
    __shared__ u16 Bsw[128 * 128];   // 32 KB

    const int tid = threadIdx.x, wid = tid >> 6, lane = tid & 63;
    const int mb = blockIdx.x * 128, nb = blockIdx.y * 128;
    const int wm = (wid >> 1) * 64, wn = (wid & 1) * 64;
    const int sr = tid >> 1;             // staging row 0..127
    const int se = (tid & 1) * 32;       // k-elem base 0/32

    const float* pA  = Af    + (long)(mb + sr) * K + se;
    const u16*   pBh = Bhi_g + (long)(nb + sr) * K + se;
    const u16*   pBl = Blo_g + (long)(nb + sr) * K + se;

    f32x16 accA[2][2] = {};
    f32x16 accB[2][2] = {};
    float4 ra[8];
    s16x8  rbh[4], rbl[4];

    auto fetch = [&](int k0) {
#pragma unroll
        for (int i = 0; i < 8; ++i) ra[i] = *(const float4*)(pA + k0 + 4 * i);
#pragma unroll
        for (int i = 0; i < 4; ++i) {
            rbh[i] = *(const s16x8*)(pBh + k0 + 8 * i);
            rbl[i] = *(const s16x8*)(pBl + k0 + 8 * i);
        }
    };
    auto stage = [&]() {
#pragma unroll
        for (int q = 0; q < 4; ++q) {
            s16x8 hh, ll;
#pragma unroll
            for (int j = 0; j < 8; ++j) {
                float f = (j < 4) ? (&ra[2 * q].x)[j] : (&ra[2 * q + 1].x)[j - 4];
                u16 h, l; split2(f, h, l);
                hh[j] = (short)h; ll[j] = (short)l;
            }
            *(s16x8*)&Asw[swz(sr, 0, se + 8 * q)] = hh;
            *(s16x8*)&Asw[swz(sr, 1, se + 8 * q)] = ll;
            *(s16x8*)&Bsw[swz(sr, 0, se + 8 * q)] = rbh[q];
            *(s16x8*)&Bsw[swz(sr, 1, se + 8 * q)] = rbl[q];
        }
    };

    fetch(0);
    const int fr = lane & 31, ko = lane >> 5;
    for (int k0 = 0; k0 < K; k0 += 64) {
        stage();
        __syncthreads();
        if (k0 + 64 < K) fetch(k0 + 64);
#pragma unroll
        for (int s = 0; s < 4; ++s) {
            const int e = s * 16 + ko * 8;
            s16x8 ah[2], al[2], bh[2], bl[2];
#pragma unroll
            for (int i = 0; i < 2; ++i) {
                ah[i] = *(const s16x8*)&Asw[swz(wm + 32 * i + fr, 0, e)];
                al[i] = *(const s16x8*)&Asw[swz(wm + 32 * i + fr, 1, e)];
                bh[i] = *(const s16x8*)&Bsw[swz(wn + 32 * i + fr, 0, e)];
                bl[i] = *(const s16x8*)&Bsw[swz(wn + 32 * i + fr, 1, e)];
            }
#pragma unroll
            for (int i = 0; i < 2; ++i)
#pragma unroll
                for (int j = 0; j < 2; ++j) {
                    accA[i][j] = __builtin_amdgcn_mfma_f32_32x32x16_bf16(ah[i], bh[j], accA[i][j], 0, 0, 0);
                    accA[i][j] = __builtin_amdgcn_mfma_f32_32x32x16_bf16(al[i], bh[j], accA[i][j], 0, 0, 0);
                    accB[i][j] = __builtin_amdgcn_mfma_f32_32x32x16_bf16(ah[i], bl[j], accB[i][j], 0, 0, 0);
                }
        }
        __syncthreads();
    }

    const int fc = lane & 31;
#pragma unroll
    for (int i = 0; i < 2; ++i)
#pragma unroll
        for (int j = 0; j < 2; ++j) {
            const int col = nb + wn + 32 * j + fc;
            const float bv = bias[col];
#pragma unroll
            for (int reg = 0; reg < 16; ++reg) {
                const int row = mb + wm + 32 * i + (reg & 3) + 8 * (reg >> 2) + 4 * (lane >> 5);
                float v = fmaxf(accA[i][j][reg] + accB[i][j][reg] + bv, 0.f);
                u16 h = f2bf_rne(v);
                const long idx = (long)row * N + col;
                Chi[idx] = h;
                Clo[idx] = f2bf_rne(v - bf2f(h));
            }
        }
}

// ---------------- combine GEMM: 64x128 tile, K=1024, bf16 hi/lo A ------------
// grid (ceil(m/64), 4). 4 waves, wave 32x64 (1x2 frags). BK=64.
__global__ __launch_bounds__(256, 2) void gemm_cmb(
    const u16* __restrict__ Ahi, const u16* __restrict__ Alo,  // [m][1024] view
    const u16* __restrict__ Whi, const u16* __restrict__ Wlo,  // [512][1024]
    const float* __restrict__ bias,
    u16* __restrict__ Ohi, u16* __restrict__ Olo,              // [m][512]
    int m)
{
    constexpr int K = 1024, N = 512;
    __shared__ u16 Asw[64 * 128];    // 16 KB
    __shared__ u16 Bsw[128 * 128];   // 32 KB

    const int tid = threadIdx.x, wid = tid >> 6, lane = tid & 63;
    const int mb = blockIdx.x * 64, nb = blockIdx.y * 128;
    const int wm = (wid >> 1) * 32, wn = (wid & 1) * 64;
    const int ar = tid >> 2, ae = (tid & 3) * 16;    // A: 4 thr/row
    const int br = tid >> 1, be = (tid & 1) * 32;    // B: 2 thr/row
    const bool aval = (mb + ar) < m;
    const long aoff = (long)(mb + ar) * K + ae;
    const long boff = (long)(nb + br) * K + be;

    f32x16 accA[2] = {};
    f32x16 accB[2] = {};
    const s16x8 zz = {0, 0, 0, 0, 0, 0, 0, 0};
    s16x8 rah[2], ral[2], rbh[4], rbl[4];

    auto fetch = [&](int k0) {
        if (aval) {
            rah[0] = *(const s16x8*)(Ahi + aoff + k0);
            rah[1] = *(const s16x8*)(Ahi + aoff + k0 + 8);
            ral[0] = *(const s16x8*)(Alo + aoff + k0);
            ral[1] = *(const s16x8*)(Alo + aoff + k0 + 8);
        } else {
            rah[0] = zz; rah[1] = zz; ral[0] = zz; ral[1] = zz;
        }
#pragma unroll
        for (int i = 0; i < 4; ++i) {
            rbh[i] = *(const s16x8*)(Whi + boff + k0 + 8 * i);
            rbl[i] = *(const s16x8*)(Wlo + boff + k0 + 8 * i);
        }
    };
    auto stage = [&]() {
#pragma unroll
        for (int q = 0; q < 2; ++q) {
            *(s16x8*)&Asw[swz(ar, 0, ae + 8 * q)] = rah[q];
            *(s16x8*)&Asw[swz(ar, 1, ae + 8 * q)] = ral[q];
        }
#pragma unroll
        for (int q = 0; q < 4; ++q) {
            *(s16x8*)&Bsw[swz(br, 0, be + 8 * q)] = rbh[q];
            *(s16x8*)&Bsw[swz(br, 1, be + 8 * q)] = rbl[q];
        }
    };

    fetch(0);
    const int fr = lane & 31, ko = lane >> 5;
    for (int k0 = 0; k0 < K; k0 += 64) {
        stage();
        __syncthreads();
        if (k0 + 64 < K) fetch(k0 + 64);
#pragma unroll
        for (int s = 0; s < 4; ++s) {
            const int e = s * 16 + ko * 8;
            s16x8 ah = *(const s16x8*)&Asw[swz(wm + fr, 0, e)];
            s16x8 al = *(const s16x8*)&Asw[swz(wm + fr, 1, e)];
#pragma unroll
            for (int j = 0; j < 2; ++j) {
                s16x8 bh = *(const s16x8*)&Bsw[swz(wn + 32 * j + fr, 0, e)];
                s16x8 bl = *(const s16x8*)&Bsw[swz(wn + 32 * j + fr, 1, e)];
                accA[j] = __builtin_amdgcn_mfma_f32_32x32x16_bf16(ah, bh, accA[j], 0, 0, 0);
                accA[j] = __builtin_amdgcn_mfma_f32_32x32x16_bf16(al, bh, accA[j], 0, 0, 0);
                accB[j] = __builtin_amdgcn_mfma_f32_32x32x16_bf16(ah, bl, accB[j], 0, 0, 0);
            }
        }
        __syncthreads();
    }

    const int fc = lane & 31;
#pragma unroll
    for (int j = 0; j < 2; ++j) {
        const int col = nb + wn + 32 * j + fc;
        const float bv = bias[col];
#pragma unroll
        for (int reg = 0; reg < 16; ++reg) {
            const int row = mb + wm + (reg & 3) + 8 * (reg >> 2) + 4 * (lane >> 5);
            if (row < m) {
                float v = fmaxf(accA[j][reg] + accB[j][reg] + bv, 0.f);
                u16 h = f2bf_rne(v);
                const long idx = (long)row * N + col;
                Ohi[idx] = h;
                Olo[idx] = f2bf_rne(v - bf2f(h));
            }
        }
    }
}

// tiny levels (m <= 32): grid (m, 2); h-row staged fp32 in LDS, 1 output/thread
__global__ __launch_bounds__(256) void tail_gemv(
    const u16* __restrict__ Hhi, const u16* __restrict__ Hlo,  // [m][1024] view
    const float* __restrict__ W,     // [512][1024] fp32
    const float* __restrict__ bias,  // [512]
    u16* __restrict__ Ohi, u16* __restrict__ Olo)              // [m][512]
{
    __shared__ float hrow[1024];
    const int row = blockIdx.x;
    const int tid = threadIdx.x;
    const int n   = blockIdx.y * 256 + tid;

    ushort4 hv = ((const ushort4*)(Hhi + (long)row * 1024))[tid];
    ushort4 lv = ((const ushort4*)(Hlo + (long)row * 1024))[tid];
    hrow[4 * tid + 0] = bf2f(hv.x) + bf2f(lv.x);
    hrow[4 * tid + 1] = bf2f(hv.y) + bf2f(lv.y);
    hrow[4 * tid + 2] = bf2f(hv.z) + bf2f(lv.z);
    hrow[4 * tid + 3] = bf2f(hv.w) + bf2f(lv.w);
    __syncthreads();

    const float* w = W + (long)n * 1024;
    float s = 0.f;
#pragma unroll 8
    for (int k = 0; k < 1024; k += 4) {
        float4 wv = *(const float4*)(w + k);
        s = fmaf(hrow[k + 0], wv.x, s);
        s = fmaf(hrow[k + 1], wv.y, s);
        s = fmaf(hrow[k + 2], wv.z, s);
        s = fmaf(hrow[k + 3], wv.w, s);
    }
    float v = fmaxf(s + bias[n], 0.f);
    u16 h = f2bf_rne(v);
    Ohi[(long)row * 512 + n] = h;
    Olo[(long)row * 512 + n] = f2bf_rne(v - bf2f(h));
}

// root projection: out[c] = dot(h_root, W_proj[c]) + b[c]
__global__ __launch_bounds__(128) void proj_kernel(
    const u16* __restrict__ hhi, const u16* __restrict__ hlo,
    const float* __restrict__ W, const float* __restrict__ b, float* __restrict__ out)
{
    const int c    = threadIdx.x >> 6;
    const int lane = threadIdx.x & 63;
    float s = 0.f;
#pragma unroll
    for (int j = 0; j < 8; ++j) {
        const int idx = lane + 64 * j;
        s = fmaf(bf2f(hhi[idx]) + bf2f(hlo[idx]), W[c * 512 + idx], s);
    }
#pragma unroll
    for (int off = 32; off > 0; off >>= 1) s += __shfl_down(s, off);
    if (lane == 0) out[c] = s + b[c];
}

extern "C" void kernel_launch(void* const* d_in, const int* in_sizes, int n_in,
                              void* d_out, int out_size, void* d_ws, size_t ws_size,
                              hipStream_t stream)
{
    const float* leaf   = (const float*)d_in[0];  // [8192,4096]
    const float* W_emb  = (const float*)d_in[1];  // [512,4096]
    const float* b_emb  = (const float*)d_in[2];  // [512]
    const float* W_comb = (const float*)d_in[3];  // [512,1024]
    const float* b_comb = (const float*)d_in[4];  // [512]
    const float* W_proj = (const float*)d_in[5];  // [2,512]
    const float* b_proj = (const float*)d_in[6];  // [2]
    float* out = (float*)d_out;

    u16* p = (u16*)d_ws;                       // ~34 MB total
    u16* WembHi  = p; p += (size_t)512 * 4096;
    u16* WembLo  = p; p += (size_t)512 * 4096;
    u16* WcombHi = p; p += (size_t)512 * 1024;
    u16* WcombLo = p; p += (size_t)512 * 1024;
    u16* h0h = p; p += (size_t)8192 * 512;
    u16* h0l = p; p += (size_t)8192 * 512;
    u16* h1h = p; p += (size_t)4096 * 512;
    u16* h1l = p; p += (size_t)4096 * 512;

    {   // weight splits
        int n4 = 512 * 4096 / 4;
        split_kernel<<<(n4 + 255) / 256, 256, 0, stream>>>(W_emb, WembHi, WembLo, n4);
        n4 = 512 * 1024 / 4;
        split_kernel<<<(n4 + 255) / 256, 256, 0, stream>>>(W_comb, WcombHi, WcombLo, n4);
    }

    // embedding: [8192,4096] -> [8192,512]
    gemm_emb<<<dim3(64, 4), 256, 0, stream>>>(
        leaf, WembHi, WembLo, b_emb, h0h, h0l);

    // combine levels m = 4096 .. 64 (per-level launches)
    u16 *ih = h0h, *il = h0l, *oh = h1h, *ol = h1l;
    for (int m = 4096; m >= 64; m >>= 1) {
        gemm_cmb<<<dim3((m + 63) / 64, 4), 256, 0, stream>>>(
            ih, il, WcombHi, WcombLo, b_comb, oh, ol, m);
        u16* t;
        t = ih; ih = oh; oh = t;
        t = il; il = ol; ol = t;
    }

    // tail levels m = 32 .. 1 as GEMV
    for (int m = 32; m >= 1; m >>= 1) {
        tail_gemv<<<dim3(m, 2), 256, 0, stream>>>(
            ih, il, W_comb, b_comb, oh, ol);
        u16* t;
        t = ih; ih = oh; oh = t;
        t = il; il = ol; ol = t;
    }

    proj_kernel<<<1, 128, 0, stream>>>(ih, il, W_proj, b_proj, out);
}

// Round 11
// 639.236 us; speedup vs baseline: 1.2858x; 1.1379x over previous
//
#include <hip/hip_runtime.h>
#include <stdint.h>

// Tree-RNN forward, split-bf16 MFMA, round 8 design (4th submit; broker timeouts).
//   h0 = relu(leaf[8192,4096] @ W_emb^T + b_emb)
//   13x: h = relu(h[m,1024] @ W_comb^T + b_comb)   (m: 4096..1)
//   out[2] = h_root @ W_proj^T + b_proj
// fp32 via 3-product split: AB ~= AhBh + AlBh + AhBl.
// (1) embed split-K=2 with fp32 atomic partials (2 blocks/CU; r7 was
// grid==CUs -> 1 wave/SIMD, latency-exposed); (2) combines rewritten as
// LDS-free k-parallel-wave GEMM (operands direct from L2, no k-loop barriers,
// no launch_bounds reg-cap spills); (3) ws region reuse keeps total at 35.7MB.

typedef float  f32x16 __attribute__((ext_vector_type(16)));
typedef short  s16x8  __attribute__((ext_vector_type(8)));
typedef unsigned short u16;

__device__ __forceinline__ u16 f2bf_rne(float f) {
    union { float f; uint32_t u; } v; v.f = f;
    return (u16)((v.u + 0x7FFFu + ((v.u >> 16) & 1u)) >> 16);
}
__device__ __forceinline__ float bf2f(u16 h) {
    union { uint32_t u; float f; } v; v.u = ((uint32_t)h) << 16;
    return v.f;
}
__device__ __forceinline__ void split2(float f, u16& h, u16& l) {
    union { float f; uint32_t u; } v; v.f = f;
    h = (u16)(v.u >> 16);                       // trunc hi
    union { uint32_t u; float f; } hf; hf.u = v.u & 0xFFFF0000u;
    l = f2bf_rne(f - hf.f);                     // RNE lo
}

// u16 index into a [rows][128] tile row: [hi 64 | lo 64] = 256 B, XOR swizzle.
// Verified round 7: SQ_LDS_BANK_CONFLICT = 0.
__device__ __forceinline__ int swz(int row, int p, int e) {
    return (row * 128 + p * 64 + e) ^ ((row & 15) << 3);
}

// fp32 -> (hi, lo) bf16 planes
__global__ __launch_bounds__(256) void split_kernel(
    const float* __restrict__ x, u16* __restrict__ hi, u16* __restrict__ lo, int n4)
{
    int i = blockIdx.x * 256 + threadIdx.x;
    if (i >= n4) return;
    float4 v = ((const float4*)x)[i];
    ushort4 h, l;
    split2(v.x, h.x, l.x);
    split2(v.y, h.y, l.y);
    split2(v.z, h.z, l.z);
    split2(v.w, h.w, l.w);
    ((ushort4*)hi)[i] = h;
    ((ushort4*)lo)[i] = l;
}

// ---------------- embedding GEMM: 128x128 tile, split-K=2, atomic partials ---
// grid (64, 4, 2) = 512 blocks (2/CU). 4 waves 2x2, wave 64x64. BK=64.
__global__ __launch_bounds__(256, 1) void gemm_emb(
    const float* __restrict__ Af,                                   // [8192][4096]
    const u16* __restrict__ Bhi_g, const u16* __restrict__ Blo_g,   // [512][4096]
    float* __restrict__ C32)                                        // [8192][512]
{
    constexpr int K = 4096, N = 512, KH = 2048;
    __shared__ u16 Asw[128 * 128];   // 32 KB
    __shared__ u16 Bsw[128 * 128];   // 32 KB

    const int tid = threadIdx.x, wid = tid >> 6, lane = tid & 63;
    const int mb = blockIdx.x * 128, nb = blockIdx.y * 128;
    const long koff = (long)blockIdx.z * KH;
    const int wm = (wid >> 1) * 64, wn = (wid & 1) * 64;
    const int sr = tid >> 1;             // staging row 0..127
    const int se = (tid & 1) * 32;       // k-elem base 0/32

    const float* pA  = Af    + (long)(mb + sr) * K + se + koff;
    const u16*   pBh = Bhi_g + (long)(nb + sr) * K + se + koff;
    const u16*   pBl = Blo_g + (long)(nb + sr) * K + se + koff;

    f32x16 accA[2][2] = {};
    f32x16 accB[2][2] = {};
    float4 ra[8];
    s16x8  rbh[4], rbl[4];

    auto fetch = [&](int k0) {
#pragma unroll
        for (int i = 0; i < 8; ++i) ra[i] = *(const float4*)(pA + k0 + 4 * i);
#pragma unroll
        for (int i = 0; i < 4; ++i) {
            rbh[i] = *(const s16x8*)(pBh + k0 + 8 * i);
            rbl[i] = *(const s16x8*)(pBl + k0 + 8 * i);
        }
    };
    auto stage = [&]() {
#pragma unroll
        for (int q = 0; q < 4; ++q) {
            s16x8 hh, ll;
#pragma unroll
            for (int j = 0; j < 8; ++j) {
                float f = (j < 4) ? (&ra[2 * q].x)[j] : (&ra[2 * q + 1].x)[j - 4];
                u16 h, l; split2(f, h, l);
                hh[j] = (short)h; ll[j] = (short)l;
            }
            *(s16x8*)&Asw[swz(sr, 0, se + 8 * q)] = hh;
            *(s16x8*)&Asw[swz(sr, 1, se + 8 * q)] = ll;
            *(s16x8*)&Bsw[swz(sr, 0, se + 8 * q)] = rbh[q];
            *(s16x8*)&Bsw[swz(sr, 1, se + 8 * q)] = rbl[q];
        }
    };

    fetch(0);
    const int fr = lane & 31, ko = lane >> 5;
    for (int k0 = 0; k0 < KH; k0 += 64) {
        stage();
        __syncthreads();
        if (k0 + 64 < KH) fetch(k0 + 64);
#pragma unroll
        for (int s = 0; s < 4; ++s) {
            const int e = s * 16 + ko * 8;
            s16x8 ah[2], al[2], bh[2], bl[2];
#pragma unroll
            for (int i = 0; i < 2; ++i) {
                ah[i] = *(const s16x8*)&Asw[swz(wm + 32 * i + fr, 0, e)];
                al[i] = *(const s16x8*)&Asw[swz(wm + 32 * i + fr, 1, e)];
                bh[i] = *(const s16x8*)&Bsw[swz(wn + 32 * i + fr, 0, e)];
                bl[i] = *(const s16x8*)&Bsw[swz(wn + 32 * i + fr, 1, e)];
            }
#pragma unroll
            for (int i = 0; i < 2; ++i)
#pragma unroll
                for (int j = 0; j < 2; ++j) {
                    accA[i][j] = __builtin_amdgcn_mfma_f32_32x32x16_bf16(ah[i], bh[j], accA[i][j], 0, 0, 0);
                    accA[i][j] = __builtin_amdgcn_mfma_f32_32x32x16_bf16(al[i], bh[j], accA[i][j], 0, 0, 0);
                    accB[i][j] = __builtin_amdgcn_mfma_f32_32x32x16_bf16(ah[i], bl[j], accB[i][j], 0, 0, 0);
                }
        }
        __syncthreads();
    }

    const int fc = lane & 31;
#pragma unroll
    for (int i = 0; i < 2; ++i)
#pragma unroll
        for (int j = 0; j < 2; ++j) {
            const int col = nb + wn + 32 * j + fc;
#pragma unroll
            for (int reg = 0; reg < 16; ++reg) {
                const int row = mb + wm + 32 * i + (reg & 3) + 8 * (reg >> 2) + 4 * (lane >> 5);
                unsafeAtomicAdd(&C32[(long)row * N + col], accA[i][j][reg] + accB[i][j][reg]);
            }
        }
}

// reduce: C32 partial sums -> bias+relu -> hi/lo planes. 8 elems/thread.
__global__ __launch_bounds__(256) void reduce_kernel(
    const float* __restrict__ C32, const float* __restrict__ bias,
    u16* __restrict__ Ohi, u16* __restrict__ Olo)
{
    const long gid  = (long)blockIdx.x * 256 + threadIdx.x;
    const long base = gid * 8;
    const int  col  = (int)(base & 511);
    float4 x0 = *(const float4*)(C32 + base);
    float4 x1 = *(const float4*)(C32 + base + 4);
    float4 b0 = *(const float4*)(bias + col);
    float4 b1 = *(const float4*)(bias + col + 4);
    float vs[8] = { x0.x + b0.x, x0.y + b0.y, x0.z + b0.z, x0.w + b0.w,
                    x1.x + b1.x, x1.y + b1.y, x1.z + b1.z, x1.w + b1.w };
    s16x8 oh, ol;
#pragma unroll
    for (int e = 0; e < 8; ++e) {
        float v = fmaxf(vs[e], 0.f);
        u16 h, l; split2(v, h, l);
        oh[e] = (short)h; ol[e] = (short)l;
    }
    *(s16x8*)(Ohi + base) = oh;
    *(s16x8*)(Olo + base) = ol;
}

// ---------------- combine GEMM: LDS-free, k-parallel waves -------------------
// 64x64 tile, grid (ceil(m/64), 8). Wave w owns K-window [256w, 256w+256).
// Operand fragments loaded DIRECTLY from global (NT layout = lane-contiguous
// 16B rows); register ping-pong prefetch; no barrier in K-loop. 64 KB LDS only
// for the final 4-way cross-wave reduce + bias/relu/split epilogue.
__global__ __launch_bounds__(256) void gemm_cmb(
    const u16* __restrict__ Ahi, const u16* __restrict__ Alo,  // [m][1024] view
    const u16* __restrict__ Whi, const u16* __restrict__ Wlo,  // [512][1024]
    const float* __restrict__ bias,
    u16* __restrict__ Ohi, u16* __restrict__ Olo,              // [m][512]
    int m)
{
    __shared__ float red[4 * 64 * 64];   // 64 KB
    const int tid = threadIdx.x, wid = tid >> 6, lane = tid & 63;
    const int fr = lane & 31, hb = lane >> 5;
    const int mb = blockIdx.x * 64, nb = blockIdx.y * 64;
    const long kw = (long)wid * 256 + hb * 8;
    const long a0 = (long)(mb + fr) * 1024 + kw;
    const long a1 = a0 + 32 * 1024;
    const long b0 = (long)(nb + fr) * 1024 + kw;
    const long b1 = b0 + 32 * 1024;

    f32x16 acc00 = {}, acc01 = {}, acc10 = {}, acc11 = {};
    s16x8 Ah[2][2], Al[2][2], Bh[2][2], Bl[2][2];

    // preload slice 0
    Ah[0][0] = *(const s16x8*)(Ahi + a0);
    Ah[0][1] = *(const s16x8*)(Ahi + a1);
    Al[0][0] = *(const s16x8*)(Alo + a0);
    Al[0][1] = *(const s16x8*)(Alo + a1);
    Bh[0][0] = *(const s16x8*)(Whi + b0);
    Bh[0][1] = *(const s16x8*)(Whi + b1);
    Bl[0][0] = *(const s16x8*)(Wlo + b0);
    Bl[0][1] = *(const s16x8*)(Wlo + b1);

#pragma unroll
    for (int s = 0; s < 16; ++s) {
        const int cur = s & 1, nxt = cur ^ 1;
        if (s + 1 < 16) {                       // prefetch next 16-k slice
            const int ko = (s + 1) * 16;
            Ah[nxt][0] = *(const s16x8*)(Ahi + a0 + ko);
            Ah[nxt][1] = *(const s16x8*)(Ahi + a1 + ko);
            Al[nxt][0] = *(const s16x8*)(Alo + a0 + ko);
            Al[nxt][1] = *(const s16x8*)(Alo + a1 + ko);
            Bh[nxt][0] = *(const s16x8*)(Whi + b0 + ko);
            Bh[nxt][1] = *(const s16x8*)(Whi + b1 + ko);
            Bl[nxt][0] = *(const s16x8*)(Wlo + b0 + ko);
            Bl[nxt][1] = *(const s16x8*)(Wlo + b1 + ko);
        }
        acc00 = __builtin_amdgcn_mfma_f32_32x32x16_bf16(Ah[cur][0], Bh[cur][0], acc00, 0, 0, 0);
        acc01 = __builtin_amdgcn_mfma_f32_32x32x16_bf16(Ah[cur][0], Bh[cur][1], acc01, 0, 0, 0);
        acc10 = __builtin_amdgcn_mfma_f32_32x32x16_bf16(Ah[cur][1], Bh[cur][0], acc10, 0, 0, 0);
        acc11 = __builtin_amdgcn_mfma_f32_32x32x16_bf16(Ah[cur][1], Bh[cur][1], acc11, 0, 0, 0);
        acc00 = __builtin_amdgcn_mfma_f32_32x32x16_bf16(Al[cur][0], Bh[cur][0], acc00, 0, 0, 0);
        acc01 = __builtin_amdgcn_mfma_f32_32x32x16_bf16(Al[cur][0], Bh[cur][1], acc01, 0, 0, 0);
        acc10 = __builtin_amdgcn_mfma_f32_32x32x16_bf16(Al[cur][1], Bh[cur][0], acc10, 0, 0, 0);
        acc11 = __builtin_amdgcn_mfma_f32_32x32x16_bf16(Al[cur][1], Bh[cur][1], acc11, 0, 0, 0);
        acc00 = __builtin_amdgcn_mfma_f32_32x32x16_bf16(Ah[cur][0], Bl[cur][0], acc00, 0, 0, 0);
        acc01 = __builtin_amdgcn_mfma_f32_32x32x16_bf16(Ah[cur][0], Bl[cur][1], acc01, 0, 0, 0);
        acc10 = __builtin_amdgcn_mfma_f32_32x32x16_bf16(Ah[cur][1], Bl[cur][0], acc10, 0, 0, 0);
        acc11 = __builtin_amdgcn_mfma_f32_32x32x16_bf16(Ah[cur][1], Bl[cur][1], acc11, 0, 0, 0);
    }

    // write per-wave partials to LDS
    float* my = red + wid * 4096;
#pragma unroll
    for (int reg = 0; reg < 16; ++reg) {
        const int rr = (reg & 3) + 8 * (reg >> 2) + 4 * hb;
        my[rr * 64 + fr]             = acc00[reg];
        my[rr * 64 + 32 + fr]        = acc01[reg];
        my[(32 + rr) * 64 + fr]      = acc10[reg];
        my[(32 + rr) * 64 + 32 + fr] = acc11[reg];
    }
    __syncthreads();

    // cross-wave reduce + bias + relu + split. thread t: col = t&63, 16 rows.
    const int c = tid & 63, rq = (tid >> 6) * 16;
    const float bv = bias[nb + c];
#pragma unroll
    for (int k = 0; k < 16; ++k) {
        const int r = rq + k;
        const int grow = mb + r;
        if (grow < m) {
            const int o = r * 64 + c;
            float sum = red[o] + red[4096 + o] + red[8192 + o] + red[12288 + o];
            float v = fmaxf(sum + bv, 0.f);
            u16 h, l; split2(v, h, l);
            Ohi[(long)grow * 512 + nb + c] = h;
            Olo[(long)grow * 512 + nb + c] = l;
        }
    }
}

// root projection: out[c] = dot(h_root, W_proj[c]) + b[c]
__global__ __launch_bounds__(128) void proj_kernel(
    const u16* __restrict__ hhi, const u16* __restrict__ hlo,
    const float* __restrict__ W, const float* __restrict__ b, float* __restrict__ out)
{
    const int c    = threadIdx.x >> 6;
    const int lane = threadIdx.x & 63;
    float s = 0.f;
#pragma unroll
    for (int j = 0; j < 8; ++j) {
        const int idx = lane + 64 * j;
        s = fmaf(bf2f(hhi[idx]) + bf2f(hlo[idx]), W[c * 512 + idx], s);
    }
#pragma unroll
    for (int off = 32; off > 0; off >>= 1) s += __shfl_down(s, off);
    if (lane == 0) out[c] = s + b[c];
}

extern "C" void kernel_launch(void* const* d_in, const int* in_sizes, int n_in,
                              void* d_out, int out_size, void* d_ws, size_t ws_size,
                              hipStream_t stream)
{
    const float* leaf   = (const float*)d_in[0];  // [8192,4096]
    const float* W_emb  = (const float*)d_in[1];  // [512,4096]
    const float* b_emb  = (const float*)d_in[2];  // [512]
    const float* W_comb = (const float*)d_in[3];  // [512,1024]
    const float* b_comb = (const float*)d_in[4];  // [512]
    const float* W_proj = (const float*)d_in[5];  // [2,512]
    const float* b_proj = (const float*)d_in[6];  // [2]
    float* out = (float*)d_out;

    // ws regions (35.7 MB total, same budget as rounds 3-7):
    // region0 [0, 8.39M u16):   Wemb splits during embed; h0 planes after reduce
    // region1 [8.39M, 9.44M):   Wcomb splits (live whole call)
    // region2 [9.44M, 17.8M):   C32 fp32 partials during embed; h1 planes after
    u16* p = (u16*)d_ws;
    u16* r0 = p;
    u16* r1 = p + 8388608;
    u16* r2 = p + 9437184;

    u16* WembHi  = r0;
    u16* WembLo  = r0 + 2097152;
    u16* h0h     = r0;                 // aliases Wemb (dead after embed)
    u16* h0l     = r0 + 4194304;
    u16* WcombHi = r1;
    u16* WcombLo = r1 + 524288;
    float* C32   = (float*)r2;         // 4,194,304 floats = 16.8 MB
    u16* h1h     = r2;                 // aliases C32 (dead after reduce)
    u16* h1l     = r2 + 2097152;

    // zero atomic-partial buffer
    hipMemsetAsync((void*)C32, 0, (size_t)4194304 * 4, stream);

    // weight splits
    split_kernel<<<2048, 256, 0, stream>>>(W_emb, WembHi, WembLo, 524288);
    split_kernel<<<512, 256, 0, stream>>>(W_comb, WcombHi, WcombLo, 131072);

    // embedding: split-K=2, atomic fp32 partials
    gemm_emb<<<dim3(64, 4, 2), 256, 0, stream>>>(leaf, WembHi, WembLo, C32);
    reduce_kernel<<<2048, 256, 0, stream>>>(C32, b_emb, h0h, h0l);

    // 13 combine levels, all via the k-parallel kernel
    u16 *ih = h0h, *il = h0l, *oh = h1h, *ol = h1l;
    for (int m = 4096; m >= 1; m >>= 1) {
        gemm_cmb<<<dim3((m + 63) / 64, 8), 256, 0, stream>>>(
            ih, il, WcombHi, WcombLo, b_comb, oh, ol, m);
        u16* t;
        t = ih; ih = oh; oh = t;
        t = il; il = ol; ol = t;
    }

    proj_kernel<<<1, 128, 0, stream>>>(ih, il, W_proj, b_proj, out);
}